// Round 9
// baseline (425.515 us; speedup 1.0000x reference)
//
#include <hip/hip_runtime.h>

#define NN 50000
#define NE 800000
#define NG 512
#define FIN 128
#define HID 256
#define NBUK 196   // buckets of 256 node ids: ceil(50000/256)

typedef short short8 __attribute__((ext_vector_type(8)));
typedef float f32x4 __attribute__((ext_vector_type(4)));
typedef unsigned short u16x8 __attribute__((ext_vector_type(8)));

static inline int cdiv(int a, int b) { return (a + b - 1) / b; }

static __device__ inline unsigned short f2bf(float f) {
    unsigned int u = __float_as_uint(f);
    unsigned int r = (u + 0x7FFF + ((u >> 16) & 1)) >> 16;  // RNE
    return (unsigned short)r;
}
static __device__ inline float bf2f(unsigned short h) {
    return __uint_as_float(((unsigned int)h) << 16);
}
static __device__ inline float bflo(unsigned int p) { return __uint_as_float(p << 16); }
static __device__ inline float bfhi(unsigned int p) { return __uint_as_float(p & 0xFFFF0000u); }

typedef __attribute__((address_space(1))) unsigned int gu32;
typedef __attribute__((address_space(3))) unsigned int lu32;
static __device__ __forceinline__ void gload16(const unsigned short* g, unsigned short* l) {
    __builtin_amdgcn_global_load_lds((const gu32*)(const void*)g, (lu32*)(void*)l, 16, 0, 0);
}

// ---- CSR build, bucket-sort style (no per-edge global atomics) ----

__global__ __launch_bounds__(256) void hist_bucket_kernel(const int* __restrict__ dst,
                                                          int* __restrict__ gbuk) {
    __shared__ int lh[NBUK];
    int tid = threadIdx.x;
    for (int j = tid; j < NBUK; j += 256) lh[j] = 0;
    __syncthreads();
    int base = blockIdx.x * 2048;
    #pragma unroll
    for (int k = 0; k < 8; ++k) {
        int i = base + k * 256 + tid;
        if (i < NE) atomicAdd(&lh[dst[i] >> 8], 1);
    }
    __syncthreads();
    for (int j = tid; j < NBUK; j += 256) if (lh[j]) atomicAdd(&gbuk[j], lh[j]);
}

// batch is sorted: goff by boundary detection, no atomics
__global__ void goff_kernel(const int* __restrict__ batch, int* __restrict__ goff) {
    int i = blockIdx.x * 256 + threadIdx.x;
    if (i >= NN) return;
    int b = batch[i];
    int pb = (i == 0) ? -1 : batch[i - 1];
    for (int g = pb + 1; g <= b; ++g) goff[g] = i;
    if (i == NN - 1) for (int g = b + 1; g <= NG; ++g) goff[g] = NN;
}

// single-block exclusive scan of gbuk[196] -> bukoff[197], plus cursor copy
__global__ void buk_scan_kernel(const int* __restrict__ gbuk, int* __restrict__ bukoff,
                                int* __restrict__ bukcur) {
    __shared__ int ws[4];
    int tid = threadIdx.x, lane = tid & 63, wid = tid >> 6;
    int v = (tid < NBUK) ? gbuk[tid] : 0;
    int incl = v;
    #pragma unroll
    for (int off = 1; off < 64; off <<= 1) {
        int u = __shfl_up(incl, off, 64);
        if (lane >= off) incl += u;
    }
    if (lane == 63) ws[wid] = incl;
    __syncthreads();
    int woff = 0;
    for (int w = 0; w < wid; ++w) woff += ws[w];
    int ex = woff + incl - v;
    if (tid < NBUK) { bukoff[tid] = ex; bukcur[tid] = ex; }
    if (tid == NBUK - 1) bukoff[NBUK] = ex + v;
}

// scatter edges into bucket-contiguous pairs[]; one global atomic per block per bucket
__global__ __launch_bounds__(256) void scatter_kernel(const int* __restrict__ src,
                                                      const int* __restrict__ dst,
                                                      int* __restrict__ bukcur,
                                                      unsigned int* __restrict__ pairs) {
    __shared__ int lh[NBUK];
    __shared__ int lbase[NBUK];
    int tid = threadIdx.x;
    for (int j = tid; j < NBUK; j += 256) lh[j] = 0;
    __syncthreads();
    int base = blockIdx.x * 2048;
    int d[8], s[8];
    #pragma unroll
    for (int k = 0; k < 8; ++k) {
        int i = base + k * 256 + tid;
        if (i < NE) {
            d[k] = dst[i]; s[k] = src[i];
            atomicAdd(&lh[d[k] >> 8], 1);
        } else d[k] = -1;
    }
    __syncthreads();
    for (int j = tid; j < NBUK; j += 256) lbase[j] = lh[j] ? atomicAdd(&bukcur[j], lh[j]) : 0;
    __syncthreads();
    for (int j = tid; j < NBUK; j += 256) lh[j] = 0;
    __syncthreads();
    #pragma unroll
    for (int k = 0; k < 8; ++k) {
        if (d[k] >= 0) {
            int b = d[k] >> 8;
            int loc = atomicAdd(&lh[b], 1);
            pairs[lbase[b] + loc] = ((unsigned int)s[k] << 16) | (unsigned int)(d[k] & 255);
        }
    }
}

// per-bucket fine CSR: row_ptr, col, dis (one block per bucket)
__global__ __launch_bounds__(256) void local_csr_kernel(const unsigned int* __restrict__ pairs,
                                                        const int* __restrict__ bukoff,
                                                        int* __restrict__ row_ptr,
                                                        int* __restrict__ col,
                                                        float* __restrict__ dis) {
    __shared__ int fcnt[256];
    __shared__ int foff[256];
    __shared__ int fws[4];
    int b = blockIdx.x, tid = threadIdx.x;
    int beg = bukoff[b], end = bukoff[b + 1];
    fcnt[tid] = 0;
    __syncthreads();
    for (int i = beg + tid; i < end; i += 256) atomicAdd(&fcnt[pairs[i] & 255], 1);
    __syncthreads();
    int lane = tid & 63, wid = tid >> 6;
    int v = fcnt[tid], incl = v;
    #pragma unroll
    for (int off = 1; off < 64; off <<= 1) {
        int u = __shfl_up(incl, off, 64);
        if (lane >= off) incl += u;
    }
    if (lane == 63) fws[wid] = incl;
    __syncthreads();
    int woff = 0;
    for (int w = 0; w < wid; ++w) woff += fws[w];
    int ex = woff + incl - v;  // exclusive fine offset
    foff[tid] = ex;
    int gid = b * 256 + tid;
    if (gid < NN) {
        row_ptr[gid] = beg + ex;
        dis[gid] = rsqrtf((float)v + 1.0f);
    }
    if (b == 0 && tid == 0) row_ptr[NN] = NE;
    __syncthreads();
    for (int i = beg + tid; i < end; i += 256) {
        unsigned int p = pairs[i];
        int loc = atomicAdd(&foff[p & 255], 1);
        col[beg + loc] = (int)(p >> 16);
    }
}

// Xs[i][f] = bf16(dis[i] * x[i][f])
__global__ void cast_scale_kernel(const float* __restrict__ x, const float* __restrict__ dis,
                                  unsigned short* __restrict__ Xs, int n4) {
    int i = blockIdx.x * 256 + threadIdx.x;
    if (i < n4) {
        float dv = dis[i >> 5];
        float4 v = ((const float4*)x)[i];
        ushort4 o;
        o.x = f2bf(dv * v.x); o.y = f2bf(dv * v.y); o.z = f2bf(dv * v.z); o.w = f2bf(dv * v.w);
        ((ushort4*)Xs)[i] = o;
    }
}

// all three weights transposed+cast in one dispatch: W [K,256] fp32 -> Wt [256,K] bf16
__global__ void tcast_all_kernel(const float* __restrict__ W1, const float* __restrict__ W2,
                                 const float* __restrict__ W3,
                                 unsigned short* __restrict__ W1t, unsigned short* __restrict__ W2t,
                                 unsigned short* __restrict__ W3t) {
    int idx = blockIdx.x * 256 + threadIdx.x;
    if (idx < FIN * 256) {
        int n = idx / FIN, k = idx - n * FIN;
        W1t[idx] = f2bf(W1[(size_t)k * 256 + n]);
    } else if (idx < FIN * 256 + HID * 256) {
        int t = idx - FIN * 256;
        int n = t / HID, k = t - n * HID;
        W2t[t] = f2bf(W2[(size_t)k * 256 + n]);
    } else {
        int t = idx - FIN * 256 - HID * 256;
        int n = t / HID, k = t - n * HID;
        W3t[t] = f2bf(W3[(size_t)k * 256 + n]);
    }
}

// 128x128 GEMM, BK=32, global_load_lds staging, LDS-bounce coalesced epilogue.
// MODE 0: Hs = bf16(dis[row]*relu(acc + bias[col]))   MODE 1: Hf = bf16(relu(acc + bias[col]))
#define CLD 136
template <int MODE>
__global__ __launch_bounds__(256) void gemm128_kernel(
        const unsigned short* __restrict__ A, const unsigned short* __restrict__ Bt,
        const float* __restrict__ dis, const float* __restrict__ bias,
        unsigned short* __restrict__ Cout, int M, int K) {
    __shared__ unsigned short smem[128 * CLD];
    unsigned short* As = smem;
    unsigned short* Bs = smem + 4096;
    const int tid = threadIdx.x;
    const int bm = blockIdx.x * 128, bn = blockIdx.y * 128;
    const int wave = tid >> 6, lane = tid & 63;
    const int l16 = lane & 15, quad = lane >> 4;
    const int wm = (wave & 1) * 64, wn = (wave >> 1) * 64;

    int srow0 = tid >> 2, skc = (tid & 3) * 8;
    int srow1 = (256 + tid) >> 2;
    int ar0 = bm + srow0; if (ar0 > M - 1) ar0 = M - 1;
    int ar1 = bm + srow1; if (ar1 > M - 1) ar1 = M - 1;

    f32x4 acc[4][4];
    #pragma unroll
    for (int i = 0; i < 4; ++i)
        #pragma unroll
        for (int j = 0; j < 4; ++j) acc[i][j] = (f32x4){0.f, 0.f, 0.f, 0.f};

    for (int k0 = 0; k0 < K; k0 += 32) {
        gload16(A + (size_t)ar0 * K + k0 + skc, &As[(size_t)tid * 8]);
        gload16(A + (size_t)ar1 * K + k0 + skc, &As[(size_t)(256 + tid) * 8]);
        gload16(Bt + (size_t)(bn + srow0) * K + k0 + skc, &Bs[(size_t)tid * 8]);
        gload16(Bt + (size_t)(bn + srow1) * K + k0 + skc, &Bs[(size_t)(256 + tid) * 8]);
        __syncthreads();
        short8 af[4], bf[4];
        #pragma unroll
        for (int mt = 0; mt < 4; ++mt) af[mt] = *(const short8*)&As[(wm + mt * 16 + l16) * 32 + quad * 8];
        #pragma unroll
        for (int nt = 0; nt < 4; ++nt) bf[nt] = *(const short8*)&Bs[(wn + nt * 16 + l16) * 32 + quad * 8];
        #pragma unroll
        for (int mt = 0; mt < 4; ++mt)
            #pragma unroll
            for (int nt = 0; nt < 4; ++nt)
                acc[mt][nt] = __builtin_amdgcn_mfma_f32_16x16x32_bf16(af[mt], bf[nt], acc[mt][nt], 0, 0, 0);
        __syncthreads();
    }
    float bv[4];
    #pragma unroll
    for (int nt = 0; nt < 4; ++nt) bv[nt] = bias[bn + wn + nt * 16 + l16];
    #pragma unroll
    for (int mt = 0; mt < 4; ++mt) {
        #pragma unroll
        for (int r = 0; r < 4; ++r) {
            int lrow = wm + mt * 16 + quad * 4 + r;
            int grow = bm + lrow; if (grow > M - 1) grow = M - 1;
            float dv = (MODE == 0) ? dis[grow] : 1.0f;
            #pragma unroll
            for (int nt = 0; nt < 4; ++nt) {
                float v = fmaxf(acc[mt][nt][r] + bv[nt], 0.f);
                if (MODE == 0) v *= dv;
                smem[lrow * CLD + wn + nt * 16 + l16] = f2bf(v);
            }
        }
    }
    __syncthreads();
    for (int c = tid; c < 2048; c += 256) {
        int lrow = c >> 4, coff = (c & 15) << 3;
        int grow = bm + lrow;
        if (grow < M)
            *(u16x8*)(Cout + (size_t)grow * HID + bn + coff) = *(const u16x8*)&smem[lrow * CLD + coff];
    }
}
#undef CLD

// layer-1 aggregation over Xs (bf16, 128 feat, 4B/lane): Xa[v] = bf16(dis[v]*(Σ_N Xs[u] + Xs[v]))
__global__ __launch_bounds__(256) void agg128_kernel(
        const unsigned short* __restrict__ Xs, const int* __restrict__ row_ptr,
        const int* __restrict__ col, const float* __restrict__ dis,
        unsigned short* __restrict__ Xa, int n) {
    int node = blockIdx.x * 4 + (threadIdx.x >> 6);
    if (node >= n) return;
    int lane = threadIdx.x & 63;
    const unsigned int* Xv = (const unsigned int*)Xs;
    unsigned int p = Xv[(size_t)node * 64 + lane];  // self loop
    float ax = bflo(p), ay = bfhi(p);
    int e = row_ptr[node], end = row_ptr[node + 1];
    for (; e + 7 < end; e += 8) {
        unsigned int m[8];
        #pragma unroll
        for (int j = 0; j < 8; ++j) m[j] = Xv[(size_t)col[e + j] * 64 + lane];
        #pragma unroll
        for (int j = 0; j < 8; ++j) { ax += bflo(m[j]); ay += bfhi(m[j]); }
    }
    for (; e < end; ++e) {
        unsigned int m = Xv[(size_t)col[e] * 64 + lane];
        ax += bflo(m); ay += bfhi(m);
    }
    float dv = dis[node];
    unsigned int o = (unsigned int)f2bf(dv * ax) | ((unsigned int)f2bf(dv * ay) << 16);
    ((unsigned int*)Xa)[(size_t)node * 64 + lane] = o;
}

// layers 2,3 aggregation, XCD-split by feature half:
// blocks with (blockIdx&7)<4 handle features 0..127 for ALL nodes; >=4 handle 128..255.
// With round-robin block->XCD dispatch, each XCD's L2 only streams one 12.8 MB half-table.
// Correctness is mapping-independent (G16) — only locality changes.
__global__ __launch_bounds__(256) void agg256x_kernel(
        const unsigned short* __restrict__ Hs, const int* __restrict__ row_ptr,
        const int* __restrict__ col, const float* __restrict__ dis,
        unsigned short* __restrict__ G, int n) {
    int b = blockIdx.x;
    int j = b & 7;
    int half = j >> 2;                       // feature half
    int nb = (b >> 3) * 4 + (j & 3);         // node-block within half [0,12500)
    int node = nb * 4 + (threadIdx.x >> 6);
    if (node >= n) return;
    int lane = threadIdx.x & 63;
    const unsigned int* Hv = (const unsigned int*)Hs;   // row = 128 uints (256 bf16)
    const int foff = half * 64 + lane;                  // uint index within row
    unsigned int p = Hv[(size_t)node * 128 + foff];     // self loop
    float ax = bflo(p), ay = bfhi(p);
    int e = row_ptr[node], end = row_ptr[node + 1];
    for (; e + 7 < end; e += 8) {
        unsigned int m[8];
        #pragma unroll
        for (int jj = 0; jj < 8; ++jj) m[jj] = Hv[(size_t)col[e + jj] * 128 + foff];
        #pragma unroll
        for (int jj = 0; jj < 8; ++jj) { ax += bflo(m[jj]); ay += bfhi(m[jj]); }
    }
    for (; e < end; ++e) {
        unsigned int m = Hv[(size_t)col[e] * 128 + foff];
        ax += bflo(m); ay += bfhi(m);
    }
    float dv = dis[node];
    unsigned int o = (unsigned int)f2bf(dv * ax) | ((unsigned int)f2bf(dv * ay) << 16);
    ((unsigned int*)G)[(size_t)node * 128 + foff] = o;
}

// one block per graph: mean-pool (bf16 Hf) + concat + FC1(relu) + FC2
__global__ __launch_bounds__(256) void pool_mlp_kernel(
        const unsigned short* __restrict__ H, const int* __restrict__ goff,
        const float* __restrict__ mol, const float* __restrict__ rings,
        const float* __restrict__ fcW1, const float* __restrict__ fcb1,
        const float* __restrict__ fcW2, const float* __restrict__ fcb2,
        float* __restrict__ out) {
    __shared__ float s_hg[258];
    __shared__ float s_t[196];
    int g = blockIdx.x, tid = threadIdx.x;
    int beg = goff[g], end = goff[g + 1];
    float acc = 0.f;
    for (int i = beg; i < end; ++i) acc += bf2f(H[(size_t)i * HID + tid]);
    s_hg[tid] = acc / fmaxf((float)(end - beg), 1.0f);
    if (tid == 0) { s_hg[256] = mol[g]; s_hg[257] = rings[g]; }
    __syncthreads();
    if (tid < 196) {
        float a = fcb1[tid];
        for (int k = 0; k < 258; ++k) a = fmaf(s_hg[k], fcW1[k * 196 + tid], a);
        s_t[tid] = fmaxf(a, 0.f);
    }
    __syncthreads();
    if (tid < 16) {
        float a = fcb2[tid];
        for (int k = 0; k < 196; ++k) a = fmaf(s_t[k], fcW2[k * 16 + tid], a);
        out[g * 16 + tid] = a;
    }
}

extern "C" void kernel_launch(void* const* d_in, const int* in_sizes, int n_in,
                              void* d_out, int out_size, void* d_ws, size_t ws_size,
                              hipStream_t stream) {
    const float* x     = (const float*)d_in[0];
    const int*   ei    = (const int*)d_in[1];
    const int*   batch = (const int*)d_in[2];
    const float* mol   = (const float*)d_in[3];
    const float* rings = (const float*)d_in[4];
    const float* W1 = (const float*)d_in[5];
    const float* b1 = (const float*)d_in[6];
    const float* W2 = (const float*)d_in[7];
    const float* b2 = (const float*)d_in[8];
    const float* W3 = (const float*)d_in[9];
    const float* b3 = (const float*)d_in[10];
    const float* fcW1 = (const float*)d_in[11];
    const float* fcb1 = (const float*)d_in[12];
    const float* fcW2 = (const float*)d_in[13];
    const float* fcb2 = (const float*)d_in[14];
    float* out = (float*)d_out;
    const int* src = ei;
    const int* dst = ei + NE;

    char* w = (char*)d_ws;
    auto alloc = [&](size_t bytes) {
        char* p = w;
        w += (bytes + 255) & ~(size_t)255;
        return p;
    };
    int*   gbuk    = (int*)alloc((size_t)NBUK * 4);
    int*   bukoff  = (int*)alloc((size_t)(NBUK + 1) * 4);
    int*   bukcur  = (int*)alloc((size_t)NBUK * 4);
    int*   row_ptr = (int*)alloc((size_t)(NN + 1) * 4);
    int*   goff    = (int*)alloc((size_t)(NG + 1) * 4);
    float* dis     = (float*)alloc((size_t)NN * 4);
    unsigned int* pairs = (unsigned int*)alloc((size_t)NE * 4);
    int*   col     = (int*)alloc((size_t)NE * 4);
    unsigned short* Xs  = (unsigned short*)alloc((size_t)NN * FIN * 2);
    unsigned short* Xa  = (unsigned short*)alloc((size_t)NN * FIN * 2);
    unsigned short* Hs  = (unsigned short*)alloc((size_t)NN * HID * 2);
    unsigned short* Ga  = (unsigned short*)alloc((size_t)NN * HID * 2);
    unsigned short* Hf  = (unsigned short*)alloc((size_t)NN * HID * 2);
    unsigned short* W1t = (unsigned short*)alloc((size_t)FIN * HID * 2);
    unsigned short* W2t = (unsigned short*)alloc((size_t)HID * HID * 2);
    unsigned short* W3t = (unsigned short*)alloc((size_t)HID * HID * 2);

    hipMemsetAsync(gbuk, 0, (size_t)NBUK * 4, stream);
    int eb = cdiv(NE, 2048);  // 391
    hist_bucket_kernel<<<eb, 256, 0, stream>>>(dst, gbuk);
    goff_kernel<<<cdiv(NN, 256), 256, 0, stream>>>(batch, goff);
    buk_scan_kernel<<<1, 256, 0, stream>>>(gbuk, bukoff, bukcur);
    scatter_kernel<<<eb, 256, 0, stream>>>(src, dst, bukcur, pairs);
    local_csr_kernel<<<NBUK, 256, 0, stream>>>(pairs, bukoff, row_ptr, col, dis);

    cast_scale_kernel<<<cdiv(NN * FIN / 4, 256), 256, 0, stream>>>(x, dis, Xs, NN * FIN / 4);
    tcast_all_kernel<<<cdiv((FIN + HID + HID) * 256, 256), 256, 0, stream>>>(W1, W2, W3, W1t, W2t, W3t);

    dim3 ggrid(cdiv(NN, 128), 2);
    int agrid = cdiv(NN, 4);
    int axgrid = cdiv(NN, 4) * 2;  // 25000: x2 for the feature-half split
    // all layers: aggregate-then-transform (aggregation commutes with @W)
    agg128_kernel<<<agrid, 256, 0, stream>>>(Xs, row_ptr, col, dis, Xa, NN);
    gemm128_kernel<0><<<ggrid, 256, 0, stream>>>(Xa, W1t, dis, b1, Hs, NN, FIN);  // Hs1 = bf16(dis*relu)
    agg256x_kernel<<<axgrid, 256, 0, stream>>>(Hs, row_ptr, col, dis, Ga, NN);     // Ga2
    gemm128_kernel<0><<<ggrid, 256, 0, stream>>>(Ga, W2t, dis, b2, Hs, NN, HID);  // Hs2
    agg256x_kernel<<<axgrid, 256, 0, stream>>>(Hs, row_ptr, col, dis, Ga, NN);     // Ga3
    gemm128_kernel<1><<<ggrid, 256, 0, stream>>>(Ga, W3t, dis, b3, Hf, NN, HID);  // Hf = bf16(relu)
    pool_mlp_kernel<<<NG, 256, 0, stream>>>(Hf, goff, mol, rings, fcW1, fcb1, fcW2, fcb2, out);
}

// Round 10
// 416.044 us; speedup vs baseline: 1.0228x; 1.0228x over previous
//
#include <hip/hip_runtime.h>

#define NN 50000
#define NE 800000
#define NG 512
#define FIN 128
#define HID 256
#define NBUK 196   // buckets of 256 node ids: ceil(50000/256)
#define BPAD 264   // B-tile LDS row stride in shorts (2-way bank aliasing only)

typedef short short8 __attribute__((ext_vector_type(8)));
typedef float f32x4 __attribute__((ext_vector_type(4)));

static inline int cdiv(int a, int b) { return (a + b - 1) / b; }

static __device__ inline unsigned short f2bf(float f) {
    unsigned int u = __float_as_uint(f);
    unsigned int r = (u + 0x7FFF + ((u >> 16) & 1)) >> 16;  // RNE
    return (unsigned short)r;
}
static __device__ inline float bf2f(unsigned short h) {
    return __uint_as_float(((unsigned int)h) << 16);
}
static __device__ inline float bflo(unsigned int p) { return __uint_as_float(p << 16); }
static __device__ inline float bfhi(unsigned int p) { return __uint_as_float(p & 0xFFFF0000u); }

typedef __attribute__((address_space(1))) unsigned int gu32;
typedef __attribute__((address_space(3))) unsigned int lu32;
static __device__ __forceinline__ void gload16(const unsigned short* g, unsigned short* l) {
    __builtin_amdgcn_global_load_lds((const gu32*)(const void*)g, (lu32*)(void*)l, 16, 0, 0);
}

// ---- CSR build, bucket-sort style (no per-edge global atomics) ----

__global__ __launch_bounds__(256) void hist_bucket_kernel(const int* __restrict__ dst,
                                                          int* __restrict__ gbuk) {
    __shared__ int lh[NBUK];
    int tid = threadIdx.x;
    for (int j = tid; j < NBUK; j += 256) lh[j] = 0;
    __syncthreads();
    int base = blockIdx.x * 2048;
    #pragma unroll
    for (int k = 0; k < 8; ++k) {
        int i = base + k * 256 + tid;
        if (i < NE) atomicAdd(&lh[dst[i] >> 8], 1);
    }
    __syncthreads();
    for (int j = tid; j < NBUK; j += 256) if (lh[j]) atomicAdd(&gbuk[j], lh[j]);
}

// batch is sorted: goff by boundary detection, no atomics
__global__ void goff_kernel(const int* __restrict__ batch, int* __restrict__ goff) {
    int i = blockIdx.x * 256 + threadIdx.x;
    if (i >= NN) return;
    int b = batch[i];
    int pb = (i == 0) ? -1 : batch[i - 1];
    for (int g = pb + 1; g <= b; ++g) goff[g] = i;
    if (i == NN - 1) for (int g = b + 1; g <= NG; ++g) goff[g] = NN;
}

// single-block exclusive scan of gbuk[196] -> bukoff[197], plus cursor copy
__global__ void buk_scan_kernel(const int* __restrict__ gbuk, int* __restrict__ bukoff,
                                int* __restrict__ bukcur) {
    __shared__ int ws[4];
    int tid = threadIdx.x, lane = tid & 63, wid = tid >> 6;
    int v = (tid < NBUK) ? gbuk[tid] : 0;
    int incl = v;
    #pragma unroll
    for (int off = 1; off < 64; off <<= 1) {
        int u = __shfl_up(incl, off, 64);
        if (lane >= off) incl += u;
    }
    if (lane == 63) ws[wid] = incl;
    __syncthreads();
    int woff = 0;
    for (int w = 0; w < wid; ++w) woff += ws[w];
    int ex = woff + incl - v;
    if (tid < NBUK) { bukoff[tid] = ex; bukcur[tid] = ex; }
    if (tid == NBUK - 1) bukoff[NBUK] = ex + v;
}

// scatter edges into bucket-contiguous pairs[]; one global atomic per block per bucket
__global__ __launch_bounds__(256) void scatter_kernel(const int* __restrict__ src,
                                                      const int* __restrict__ dst,
                                                      int* __restrict__ bukcur,
                                                      unsigned int* __restrict__ pairs) {
    __shared__ int lh[NBUK];
    __shared__ int lbase[NBUK];
    int tid = threadIdx.x;
    for (int j = tid; j < NBUK; j += 256) lh[j] = 0;
    __syncthreads();
    int base = blockIdx.x * 2048;
    int d[8], s[8];
    #pragma unroll
    for (int k = 0; k < 8; ++k) {
        int i = base + k * 256 + tid;
        if (i < NE) {
            d[k] = dst[i]; s[k] = src[i];
            atomicAdd(&lh[d[k] >> 8], 1);
        } else d[k] = -1;
    }
    __syncthreads();
    for (int j = tid; j < NBUK; j += 256) lbase[j] = lh[j] ? atomicAdd(&bukcur[j], lh[j]) : 0;
    __syncthreads();
    for (int j = tid; j < NBUK; j += 256) lh[j] = 0;
    __syncthreads();
    #pragma unroll
    for (int k = 0; k < 8; ++k) {
        if (d[k] >= 0) {
            int b = d[k] >> 8;
            int loc = atomicAdd(&lh[b], 1);
            pairs[lbase[b] + loc] = ((unsigned int)s[k] << 16) | (unsigned int)(d[k] & 255);
        }
    }
}

// per-bucket fine CSR: row_ptr, col, dis (one block per bucket)
__global__ __launch_bounds__(256) void local_csr_kernel(const unsigned int* __restrict__ pairs,
                                                        const int* __restrict__ bukoff,
                                                        int* __restrict__ row_ptr,
                                                        int* __restrict__ col,
                                                        float* __restrict__ dis) {
    __shared__ int fcnt[256];
    __shared__ int foff[256];
    __shared__ int fws[4];
    int b = blockIdx.x, tid = threadIdx.x;
    int beg = bukoff[b], end = bukoff[b + 1];
    fcnt[tid] = 0;
    __syncthreads();
    for (int i = beg + tid; i < end; i += 256) atomicAdd(&fcnt[pairs[i] & 255], 1);
    __syncthreads();
    int lane = tid & 63, wid = tid >> 6;
    int v = fcnt[tid], incl = v;
    #pragma unroll
    for (int off = 1; off < 64; off <<= 1) {
        int u = __shfl_up(incl, off, 64);
        if (lane >= off) incl += u;
    }
    if (lane == 63) fws[wid] = incl;
    __syncthreads();
    int woff = 0;
    for (int w = 0; w < wid; ++w) woff += fws[w];
    int ex = woff + incl - v;  // exclusive fine offset
    foff[tid] = ex;
    int gid = b * 256 + tid;
    if (gid < NN) {
        row_ptr[gid] = beg + ex;
        dis[gid] = rsqrtf((float)v + 1.0f);
    }
    if (b == 0 && tid == 0) row_ptr[NN] = NE;
    __syncthreads();
    for (int i = beg + tid; i < end; i += 256) {
        unsigned int p = pairs[i];
        int loc = atomicAdd(&foff[p & 255], 1);
        col[beg + loc] = (int)(p >> 16);
    }
}

// Xs[i][f] = bf16(dis[i] * x[i][f])
__global__ void cast_scale_kernel(const float* __restrict__ x, const float* __restrict__ dis,
                                  unsigned short* __restrict__ Xs, int n4) {
    int i = blockIdx.x * 256 + threadIdx.x;
    if (i < n4) {
        float dv = dis[i >> 5];
        float4 v = ((const float4*)x)[i];
        ushort4 o;
        o.x = f2bf(dv * v.x); o.y = f2bf(dv * v.y); o.z = f2bf(dv * v.z); o.w = f2bf(dv * v.w);
        ((ushort4*)Xs)[i] = o;
    }
}

// all three weights transposed+cast in one dispatch: W [K,256] fp32 -> Wt [256,K] bf16
__global__ void tcast_all_kernel(const float* __restrict__ W1, const float* __restrict__ W2,
                                 const float* __restrict__ W3,
                                 unsigned short* __restrict__ W1t, unsigned short* __restrict__ W2t,
                                 unsigned short* __restrict__ W3t) {
    int idx = blockIdx.x * 256 + threadIdx.x;
    if (idx < FIN * 256) {
        int n = idx / FIN, k = idx - n * FIN;
        W1t[idx] = f2bf(W1[(size_t)k * 256 + n]);
    } else if (idx < FIN * 256 + HID * 256) {
        int t = idx - FIN * 256;
        int n = t / HID, k = t - n * HID;
        W2t[t] = f2bf(W2[(size_t)k * 256 + n]);
    } else {
        int t = idx - FIN * 256 - HID * 256;
        int n = t / HID, k = t - n * HID;
        W3t[t] = f2bf(W3[(size_t)k * 256 + n]);
    }
}

// B-resident 128x128 GEMM. B half-tile (128 N-rows x K) staged ONCE in padded LDS;
// K-loop stages only A via global_load_lds. Grid = 512 (2 blocks/CU); each block
// grid-strides over tiles t ordered mt-major (t = mt*2 + nhalf), so t and t+512
// share nhalf -> B staged exactly once per block, no scheduling tail.
// MODE 0: Hs = bf16(dis[row]*relu(acc + bias[col]))   MODE 1: Hf = bf16(relu(acc + bias[col]))
template <int MODE>
__global__ __launch_bounds__(256) void gemm_bres_kernel(
        const unsigned short* __restrict__ A, const unsigned short* __restrict__ Bt,
        const float* __restrict__ dis, const float* __restrict__ bias,
        unsigned short* __restrict__ Cout, int M, int K, int ntiles) {
    __shared__ unsigned short Bs[128 * BPAD];  // 67.6 KB
    __shared__ unsigned short As[128 * 32];    // 8 KB  (unpadded: glds constraint)
    const int tid = threadIdx.x;
    const int wave = tid >> 6, lane = tid & 63;
    const int l16 = lane & 15, quad = lane >> 4;
    const int wm = (wave & 1) * 64, wn = (wave >> 1) * 64;

    const int nhalf = blockIdx.x & 1;          // same for all this block's tiles
    const int bn = nhalf * 128;

    // stage B(nhalf) once: rows bn..bn+127 of Bt, each K shorts, padded stride
    const int kc = K >> 3;  // 16B chunks per row
    for (int c = tid; c < 128 * kc; c += 256) {
        int n = c / kc, k8 = (c - n * kc) * 8;
        *(uint4*)&Bs[n * BPAD + k8] = *(const uint4*)(Bt + (size_t)(bn + n) * K + k8);
    }
    float bv[4];
    #pragma unroll
    for (int nt = 0; nt < 4; ++nt) bv[nt] = bias[bn + wn + nt * 16 + l16];

    const int srow0 = tid >> 2, skc = (tid & 3) * 8;
    const int srow1 = (256 + tid) >> 2;

    for (int t = blockIdx.x; t < ntiles; t += gridDim.x) {
        const int bm = (t >> 1) * 128;
        int ar0 = bm + srow0; if (ar0 > M - 1) ar0 = M - 1;
        int ar1 = bm + srow1; if (ar1 > M - 1) ar1 = M - 1;

        f32x4 acc[4][4];
        #pragma unroll
        for (int i = 0; i < 4; ++i)
            #pragma unroll
            for (int j = 0; j < 4; ++j) acc[i][j] = (f32x4){0.f, 0.f, 0.f, 0.f};

        for (int k0 = 0; k0 < K; k0 += 32) {
            gload16(A + (size_t)ar0 * K + k0 + skc, &As[(size_t)tid * 8]);
            gload16(A + (size_t)ar1 * K + k0 + skc, &As[(size_t)(256 + tid) * 8]);
            __syncthreads();   // also covers initial B-stage visibility
            short8 af[4], bf[4];
            #pragma unroll
            for (int mt = 0; mt < 4; ++mt) af[mt] = *(const short8*)&As[(wm + mt * 16 + l16) * 32 + quad * 8];
            #pragma unroll
            for (int nt = 0; nt < 4; ++nt) bf[nt] = *(const short8*)&Bs[(wn + nt * 16 + l16) * BPAD + k0 + quad * 8];
            #pragma unroll
            for (int mt = 0; mt < 4; ++mt)
                #pragma unroll
                for (int nt = 0; nt < 4; ++nt)
                    acc[mt][nt] = __builtin_amdgcn_mfma_f32_16x16x32_bf16(af[mt], bf[nt], acc[mt][nt], 0, 0, 0);
            __syncthreads();
        }
        // epilogue: C/D col = l16 (+16nt +wn +bn), row = quad*4 + r (+16mt +wm +bm)
        #pragma unroll
        for (int mt = 0; mt < 4; ++mt) {
            #pragma unroll
            for (int r = 0; r < 4; ++r) {
                int row = bm + wm + mt * 16 + quad * 4 + r;
                if (row < M) {
                    unsigned short* crow = Cout + (size_t)row * HID + bn + wn + l16;
                    if (MODE == 0) {
                        float dv = dis[row];
                        #pragma unroll
                        for (int nt = 0; nt < 4; ++nt)
                            crow[nt * 16] = f2bf(dv * fmaxf(acc[mt][nt][r] + bv[nt], 0.f));
                    } else {
                        #pragma unroll
                        for (int nt = 0; nt < 4; ++nt)
                            crow[nt * 16] = f2bf(fmaxf(acc[mt][nt][r] + bv[nt], 0.f));
                    }
                }
            }
        }
    }
}

// layer-1 aggregation over Xs (bf16, 128 feat, 4B/lane): Xa[v] = bf16(dis[v]*(Σ_N Xs[u] + Xs[v]))
__global__ __launch_bounds__(256) void agg128_kernel(
        const unsigned short* __restrict__ Xs, const int* __restrict__ row_ptr,
        const int* __restrict__ col, const float* __restrict__ dis,
        unsigned short* __restrict__ Xa, int n) {
    int node = blockIdx.x * 4 + (threadIdx.x >> 6);
    if (node >= n) return;
    int lane = threadIdx.x & 63;
    const unsigned int* Xv = (const unsigned int*)Xs;
    unsigned int p = Xv[(size_t)node * 64 + lane];  // self loop
    float ax = bflo(p), ay = bfhi(p);
    int e = row_ptr[node], end = row_ptr[node + 1];
    for (; e + 7 < end; e += 8) {
        unsigned int m[8];
        #pragma unroll
        for (int j = 0; j < 8; ++j) m[j] = Xv[(size_t)col[e + j] * 64 + lane];
        #pragma unroll
        for (int j = 0; j < 8; ++j) { ax += bflo(m[j]); ay += bfhi(m[j]); }
    }
    for (; e < end; ++e) {
        unsigned int m = Xv[(size_t)col[e] * 64 + lane];
        ax += bflo(m); ay += bfhi(m);
    }
    float dv = dis[node];
    unsigned int o = (unsigned int)f2bf(dv * ax) | ((unsigned int)f2bf(dv * ay) << 16);
    ((unsigned int*)Xa)[(size_t)node * 64 + lane] = o;
}

// layers 2,3 aggregation over Hs (bf16, 256 feat, 8B/lane): G[v] = bf16(dis[v]*(Σ_N Hs[u] + Hs[v]))
__global__ __launch_bounds__(256) void agg256_kernel(
        const unsigned short* __restrict__ Hs, const int* __restrict__ row_ptr,
        const int* __restrict__ col, const float* __restrict__ dis,
        unsigned short* __restrict__ G, int n) {
    int node = blockIdx.x * 4 + (threadIdx.x >> 6);
    if (node >= n) return;
    int lane = threadIdx.x & 63;
    const uint2* Hv = (const uint2*)Hs;
    uint2 p = Hv[(size_t)node * 64 + lane];
    float4 acc = make_float4(bflo(p.x), bfhi(p.x), bflo(p.y), bfhi(p.y));
    int e = row_ptr[node], end = row_ptr[node + 1];
    for (; e + 7 < end; e += 8) {
        uint2 m[8];
        #pragma unroll
        for (int j = 0; j < 8; ++j) m[j] = Hv[(size_t)col[e + j] * 64 + lane];
        #pragma unroll
        for (int j = 0; j < 8; ++j) {
            acc.x += bflo(m[j].x); acc.y += bfhi(m[j].x);
            acc.z += bflo(m[j].y); acc.w += bfhi(m[j].y);
        }
    }
    for (; e < end; ++e) {
        uint2 m = Hv[(size_t)col[e] * 64 + lane];
        acc.x += bflo(m.x); acc.y += bfhi(m.x);
        acc.z += bflo(m.y); acc.w += bfhi(m.y);
    }
    float dv = dis[node];
    ushort4 o;
    o.x = f2bf(dv * acc.x); o.y = f2bf(dv * acc.y);
    o.z = f2bf(dv * acc.z); o.w = f2bf(dv * acc.w);
    ((ushort4*)G)[(size_t)node * 64 + lane] = o;
}

// one block per graph: mean-pool (bf16 Hf) + concat + FC1(relu) + FC2
__global__ __launch_bounds__(256) void pool_mlp_kernel(
        const unsigned short* __restrict__ H, const int* __restrict__ goff,
        const float* __restrict__ mol, const float* __restrict__ rings,
        const float* __restrict__ fcW1, const float* __restrict__ fcb1,
        const float* __restrict__ fcW2, const float* __restrict__ fcb2,
        float* __restrict__ out) {
    __shared__ float s_hg[258];
    __shared__ float s_t[196];
    int g = blockIdx.x, tid = threadIdx.x;
    int beg = goff[g], end = goff[g + 1];
    float acc = 0.f;
    for (int i = beg; i < end; ++i) acc += bf2f(H[(size_t)i * HID + tid]);
    s_hg[tid] = acc / fmaxf((float)(end - beg), 1.0f);
    if (tid == 0) { s_hg[256] = mol[g]; s_hg[257] = rings[g]; }
    __syncthreads();
    if (tid < 196) {
        float a = fcb1[tid];
        for (int k = 0; k < 258; ++k) a = fmaf(s_hg[k], fcW1[k * 196 + tid], a);
        s_t[tid] = fmaxf(a, 0.f);
    }
    __syncthreads();
    if (tid < 16) {
        float a = fcb2[tid];
        for (int k = 0; k < 196; ++k) a = fmaf(s_t[k], fcW2[k * 16 + tid], a);
        out[g * 16 + tid] = a;
    }
}

extern "C" void kernel_launch(void* const* d_in, const int* in_sizes, int n_in,
                              void* d_out, int out_size, void* d_ws, size_t ws_size,
                              hipStream_t stream) {
    const float* x     = (const float*)d_in[0];
    const int*   ei    = (const int*)d_in[1];
    const int*   batch = (const int*)d_in[2];
    const float* mol   = (const float*)d_in[3];
    const float* rings = (const float*)d_in[4];
    const float* W1 = (const float*)d_in[5];
    const float* b1 = (const float*)d_in[6];
    const float* W2 = (const float*)d_in[7];
    const float* b2 = (const float*)d_in[8];
    const float* W3 = (const float*)d_in[9];
    const float* b3 = (const float*)d_in[10];
    const float* fcW1 = (const float*)d_in[11];
    const float* fcb1 = (const float*)d_in[12];
    const float* fcW2 = (const float*)d_in[13];
    const float* fcb2 = (const float*)d_in[14];
    float* out = (float*)d_out;
    const int* src = ei;
    const int* dst = ei + NE;

    char* w = (char*)d_ws;
    auto alloc = [&](size_t bytes) {
        char* p = w;
        w += (bytes + 255) & ~(size_t)255;
        return p;
    };
    int*   gbuk    = (int*)alloc((size_t)NBUK * 4);
    int*   bukoff  = (int*)alloc((size_t)(NBUK + 1) * 4);
    int*   bukcur  = (int*)alloc((size_t)NBUK * 4);
    int*   row_ptr = (int*)alloc((size_t)(NN + 1) * 4);
    int*   goff    = (int*)alloc((size_t)(NG + 1) * 4);
    float* dis     = (float*)alloc((size_t)NN * 4);
    unsigned int* pairs = (unsigned int*)alloc((size_t)NE * 4);
    int*   col     = (int*)alloc((size_t)NE * 4);
    unsigned short* Xs  = (unsigned short*)alloc((size_t)NN * FIN * 2);
    unsigned short* Xa  = (unsigned short*)alloc((size_t)NN * FIN * 2);
    unsigned short* Hs  = (unsigned short*)alloc((size_t)NN * HID * 2);
    unsigned short* Ga  = (unsigned short*)alloc((size_t)NN * HID * 2);
    unsigned short* Hf  = (unsigned short*)alloc((size_t)NN * HID * 2);
    unsigned short* W1t = (unsigned short*)alloc((size_t)FIN * HID * 2);
    unsigned short* W2t = (unsigned short*)alloc((size_t)HID * HID * 2);
    unsigned short* W3t = (unsigned short*)alloc((size_t)HID * HID * 2);

    hipMemsetAsync(gbuk, 0, (size_t)NBUK * 4, stream);
    int eb = cdiv(NE, 2048);  // 391
    hist_bucket_kernel<<<eb, 256, 0, stream>>>(dst, gbuk);
    goff_kernel<<<cdiv(NN, 256), 256, 0, stream>>>(batch, goff);
    buk_scan_kernel<<<1, 256, 0, stream>>>(gbuk, bukoff, bukcur);
    scatter_kernel<<<eb, 256, 0, stream>>>(src, dst, bukcur, pairs);
    local_csr_kernel<<<NBUK, 256, 0, stream>>>(pairs, bukoff, row_ptr, col, dis);

    cast_scale_kernel<<<cdiv(NN * FIN / 4, 256), 256, 0, stream>>>(x, dis, Xs, NN * FIN / 4);
    tcast_all_kernel<<<cdiv((FIN + HID + HID) * 256, 256), 256, 0, stream>>>(W1, W2, W3, W1t, W2t, W3t);

    const int ntiles = cdiv(NN, 128) * 2;  // 782, ordered t = mt*2 + nhalf
    const int ggrid = 512;                 // 2 blocks/CU, even -> nhalf invariant per block
    int agrid = cdiv(NN, 4);
    // all layers: aggregate-then-transform (aggregation commutes with @W)
    agg128_kernel<<<agrid, 256, 0, stream>>>(Xs, row_ptr, col, dis, Xa, NN);
    gemm_bres_kernel<0><<<ggrid, 256, 0, stream>>>(Xa, W1t, dis, b1, Hs, NN, FIN, ntiles);
    agg256_kernel<<<agrid, 256, 0, stream>>>(Hs, row_ptr, col, dis, Ga, NN);
    gemm_bres_kernel<0><<<ggrid, 256, 0, stream>>>(Ga, W2t, dis, b2, Hs, NN, HID, ntiles);
    agg256_kernel<<<agrid, 256, 0, stream>>>(Hs, row_ptr, col, dis, Ga, NN);
    gemm_bres_kernel<1><<<ggrid, 256, 0, stream>>>(Ga, W3t, dis, b3, Hf, NN, HID, ntiles);
    pool_mlp_kernel<<<NG, 256, 0, stream>>>(Hf, goff, mol, rings, fcW1, fcb1, fcW2, fcb2, out);
}

// Round 11
// 408.714 us; speedup vs baseline: 1.0411x; 1.0179x over previous
//
#include <hip/hip_runtime.h>

#define NN 50000
#define NE 800000
#define NG 512
#define FIN 128
#define HID 256
#define NBUK 196   // buckets of 256 node ids: ceil(50000/256)

typedef short short8 __attribute__((ext_vector_type(8)));
typedef float f32x4 __attribute__((ext_vector_type(4)));

static inline int cdiv(int a, int b) { return (a + b - 1) / b; }

static __device__ inline unsigned short f2bf(float f) {
    unsigned int u = __float_as_uint(f);
    unsigned int r = (u + 0x7FFF + ((u >> 16) & 1)) >> 16;  // RNE
    return (unsigned short)r;
}
static __device__ inline float bf2f(unsigned short h) {
    return __uint_as_float(((unsigned int)h) << 16);
}
static __device__ inline float bflo(unsigned int p) { return __uint_as_float(p << 16); }
static __device__ inline float bfhi(unsigned int p) { return __uint_as_float(p & 0xFFFF0000u); }

typedef __attribute__((address_space(1))) unsigned int gu32;
typedef __attribute__((address_space(3))) unsigned int lu32;
static __device__ __forceinline__ void gload16(const unsigned short* g, unsigned short* l) {
    __builtin_amdgcn_global_load_lds((const gu32*)(const void*)g, (lu32*)(void*)l, 16, 0, 0);
}

// ---- CSR build, bucket-sort style (no per-edge global atomics) ----

__global__ __launch_bounds__(256) void hist_bucket_kernel(const int* __restrict__ dst,
                                                          int* __restrict__ gbuk) {
    __shared__ int lh[NBUK];
    int tid = threadIdx.x;
    for (int j = tid; j < NBUK; j += 256) lh[j] = 0;
    __syncthreads();
    int base = blockIdx.x * 2048;
    #pragma unroll
    for (int k = 0; k < 8; ++k) {
        int i = base + k * 256 + tid;
        if (i < NE) atomicAdd(&lh[dst[i] >> 8], 1);
    }
    __syncthreads();
    for (int j = tid; j < NBUK; j += 256) if (lh[j]) atomicAdd(&gbuk[j], lh[j]);
}

// fused: blocks 0..195 do goff boundary detection; block 196 scans gbuk -> bukoff/bukcur
__global__ void goff_bukscan_kernel(const int* __restrict__ batch, int* __restrict__ goff,
                                    const int* __restrict__ gbuk, int* __restrict__ bukoff,
                                    int* __restrict__ bukcur) {
    if (blockIdx.x < 196) {
        int i = blockIdx.x * 256 + threadIdx.x;
        if (i >= NN) return;
        int b = batch[i];
        int pb = (i == 0) ? -1 : batch[i - 1];
        for (int g = pb + 1; g <= b; ++g) goff[g] = i;
        if (i == NN - 1) for (int g = b + 1; g <= NG; ++g) goff[g] = NN;
    } else {
        __shared__ int ws[4];
        int tid = threadIdx.x, lane = tid & 63, wid = tid >> 6;
        int v = (tid < NBUK) ? gbuk[tid] : 0;
        int incl = v;
        #pragma unroll
        for (int off = 1; off < 64; off <<= 1) {
            int u = __shfl_up(incl, off, 64);
            if (lane >= off) incl += u;
        }
        if (lane == 63) ws[wid] = incl;
        __syncthreads();
        int woff = 0;
        for (int w = 0; w < wid; ++w) woff += ws[w];
        int ex = woff + incl - v;
        if (tid < NBUK) { bukoff[tid] = ex; bukcur[tid] = ex; }
        if (tid == NBUK - 1) bukoff[NBUK] = ex + v;
    }
}

// scatter edges into bucket-contiguous pairs[]; one global atomic per block per bucket
__global__ __launch_bounds__(256) void scatter_kernel(const int* __restrict__ src,
                                                      const int* __restrict__ dst,
                                                      int* __restrict__ bukcur,
                                                      unsigned int* __restrict__ pairs) {
    __shared__ int lh[NBUK];
    __shared__ int lbase[NBUK];
    int tid = threadIdx.x;
    for (int j = tid; j < NBUK; j += 256) lh[j] = 0;
    __syncthreads();
    int base = blockIdx.x * 2048;
    int d[8], s[8];
    #pragma unroll
    for (int k = 0; k < 8; ++k) {
        int i = base + k * 256 + tid;
        if (i < NE) {
            d[k] = dst[i]; s[k] = src[i];
            atomicAdd(&lh[d[k] >> 8], 1);
        } else d[k] = -1;
    }
    __syncthreads();
    for (int j = tid; j < NBUK; j += 256) lbase[j] = lh[j] ? atomicAdd(&bukcur[j], lh[j]) : 0;
    __syncthreads();
    for (int j = tid; j < NBUK; j += 256) lh[j] = 0;
    __syncthreads();
    #pragma unroll
    for (int k = 0; k < 8; ++k) {
        if (d[k] >= 0) {
            int b = d[k] >> 8;
            int loc = atomicAdd(&lh[b], 1);
            pairs[lbase[b] + loc] = ((unsigned int)s[k] << 16) | (unsigned int)(d[k] & 255);
        }
    }
}

// per-bucket fine CSR: row_ptr, col, dis (one block per bucket)
__global__ __launch_bounds__(256) void local_csr_kernel(const unsigned int* __restrict__ pairs,
                                                        const int* __restrict__ bukoff,
                                                        int* __restrict__ row_ptr,
                                                        int* __restrict__ col,
                                                        float* __restrict__ dis) {
    __shared__ int fcnt[256];
    __shared__ int foff[256];
    __shared__ int fws[4];
    int b = blockIdx.x, tid = threadIdx.x;
    int beg = bukoff[b], end = bukoff[b + 1];
    fcnt[tid] = 0;
    __syncthreads();
    for (int i = beg + tid; i < end; i += 256) atomicAdd(&fcnt[pairs[i] & 255], 1);
    __syncthreads();
    int lane = tid & 63, wid = tid >> 6;
    int v = fcnt[tid], incl = v;
    #pragma unroll
    for (int off = 1; off < 64; off <<= 1) {
        int u = __shfl_up(incl, off, 64);
        if (lane >= off) incl += u;
    }
    if (lane == 63) fws[wid] = incl;
    __syncthreads();
    int woff = 0;
    for (int w = 0; w < wid; ++w) woff += fws[w];
    int ex = woff + incl - v;  // exclusive fine offset
    foff[tid] = ex;
    int gid = b * 256 + tid;
    if (gid < NN) {
        row_ptr[gid] = beg + ex;
        dis[gid] = rsqrtf((float)v + 1.0f);
    }
    if (b == 0 && tid == 0) row_ptr[NN] = NE;
    __syncthreads();
    for (int i = beg + tid; i < end; i += 256) {
        unsigned int p = pairs[i];
        int loc = atomicAdd(&foff[p & 255], 1);
        col[beg + loc] = (int)(p >> 16);
    }
}

// fused: Xs[i][f] = bf16(dis[i]*x[i][f])  AND  W1/W2/W3 transpose-cast
#define CAST1 (NN * FIN / 4)   // 1,600,000 float4 units
__global__ void castall_kernel(const float* __restrict__ x, const float* __restrict__ dis,
                               unsigned short* __restrict__ Xs,
                               const float* __restrict__ W1, const float* __restrict__ W2,
                               const float* __restrict__ W3,
                               unsigned short* __restrict__ W1t, unsigned short* __restrict__ W2t,
                               unsigned short* __restrict__ W3t) {
    int idx = blockIdx.x * 256 + threadIdx.x;
    if (idx < CAST1) {
        float dv = dis[idx >> 5];
        float4 v = ((const float4*)x)[idx];
        ushort4 o;
        o.x = f2bf(dv * v.x); o.y = f2bf(dv * v.y); o.z = f2bf(dv * v.z); o.w = f2bf(dv * v.w);
        ((ushort4*)Xs)[idx] = o;
        return;
    }
    int t = idx - CAST1;
    if (t < FIN * 256) {
        int n = t / FIN, k = t - n * FIN;
        W1t[t] = f2bf(W1[(size_t)k * 256 + n]);
    } else if (t < FIN * 256 + HID * 256) {
        int t2 = t - FIN * 256;
        int n = t2 / HID, k = t2 - n * HID;
        W2t[t2] = f2bf(W2[(size_t)k * 256 + n]);
    } else if (t < FIN * 256 + 2 * HID * 256) {
        int t3 = t - FIN * 256 - HID * 256;
        int n = t3 / HID, k = t3 - n * HID;
        W3t[t3] = f2bf(W3[(size_t)k * 256 + n]);
    }
}

// 128x128 GEMM, BK=32, DOUBLE-BUFFERED global_load_lds staging.
// Key: barrier sits BEFORE the next glds issue, so it drains only the previous
// iter's loads (in flight for a full compute-iter) — drain mostly hidden.
// MODE 0: Hs = bf16(dis[row]*relu(acc + bias[col]))   MODE 1: Hf = bf16(relu(acc + bias[col]))
template <int MODE>
__global__ __launch_bounds__(256) void gemm128_kernel(
        const unsigned short* __restrict__ A, const unsigned short* __restrict__ Bt,
        const float* __restrict__ dis, const float* __restrict__ bias,
        unsigned short* __restrict__ Cout, int M, int K) {
    __shared__ unsigned short As[2][128 * 32];   // unpadded (glds lane-contiguous constraint)
    __shared__ unsigned short Bs[2][128 * 32];
    const int tid = threadIdx.x;
    const int bm = blockIdx.x * 128, bn = blockIdx.y * 128;
    const int wave = tid >> 6, lane = tid & 63;
    const int l16 = lane & 15, quad = lane >> 4;
    const int wm = (wave & 1) * 64, wn = (wave >> 1) * 64;

    const int srow0 = tid >> 2, skc = (tid & 3) * 8;
    const int srow1 = (256 + tid) >> 2;
    int ar0 = bm + srow0; if (ar0 > M - 1) ar0 = M - 1;
    int ar1 = bm + srow1; if (ar1 > M - 1) ar1 = M - 1;
    const unsigned short* a0 = A + (size_t)ar0 * K + skc;
    const unsigned short* a1 = A + (size_t)ar1 * K + skc;
    const unsigned short* b0 = Bt + (size_t)(bn + srow0) * K + skc;
    const unsigned short* b1 = Bt + (size_t)(bn + srow1) * K + skc;

    f32x4 acc[4][4];
    #pragma unroll
    for (int i = 0; i < 4; ++i)
        #pragma unroll
        for (int j = 0; j < 4; ++j) acc[i][j] = (f32x4){0.f, 0.f, 0.f, 0.f};

    // prologue: stage k0=0 into buffer 0
    gload16(a0, &As[0][(size_t)tid * 8]);
    gload16(a1, &As[0][(size_t)(256 + tid) * 8]);
    gload16(b0, &Bs[0][(size_t)tid * 8]);
    gload16(b1, &Bs[0][(size_t)(256 + tid) * 8]);

    int cur = 0;
    for (int k0 = 0; k0 < K; k0 += 32) {
        __syncthreads();   // drains glds into `cur` (issued one full iter ago, except first)
        int nxt = cur ^ 1;
        if (k0 + 32 < K) {
            gload16(a0 + k0 + 32, &As[nxt][(size_t)tid * 8]);
            gload16(a1 + k0 + 32, &As[nxt][(size_t)(256 + tid) * 8]);
            gload16(b0 + k0 + 32, &Bs[nxt][(size_t)tid * 8]);
            gload16(b1 + k0 + 32, &Bs[nxt][(size_t)(256 + tid) * 8]);
        }
        short8 af[4], bf[4];
        #pragma unroll
        for (int mt = 0; mt < 4; ++mt) af[mt] = *(const short8*)&As[cur][(wm + mt * 16 + l16) * 32 + quad * 8];
        #pragma unroll
        for (int nt = 0; nt < 4; ++nt) bf[nt] = *(const short8*)&Bs[cur][(wn + nt * 16 + l16) * 32 + quad * 8];
        #pragma unroll
        for (int mt = 0; mt < 4; ++mt)
            #pragma unroll
            for (int nt = 0; nt < 4; ++nt)
                acc[mt][nt] = __builtin_amdgcn_mfma_f32_16x16x32_bf16(af[mt], bf[nt], acc[mt][nt], 0, 0, 0);
        cur = nxt;
    }
    // epilogue: C/D col = l16 (+16nt +wn), row = quad*4 + r (+16mt +wm)
    float bv[4];
    #pragma unroll
    for (int nt = 0; nt < 4; ++nt) bv[nt] = bias[bn + wn + nt * 16 + l16];
    #pragma unroll
    for (int mt = 0; mt < 4; ++mt) {
        #pragma unroll
        for (int r = 0; r < 4; ++r) {
            int row = bm + wm + mt * 16 + quad * 4 + r;
            if (row < M) {
                unsigned short* crow = Cout + (size_t)row * HID + bn + wn + l16;
                if (MODE == 0) {
                    float dv = dis[row];
                    #pragma unroll
                    for (int nt = 0; nt < 4; ++nt)
                        crow[nt * 16] = f2bf(dv * fmaxf(acc[mt][nt][r] + bv[nt], 0.f));
                } else {
                    #pragma unroll
                    for (int nt = 0; nt < 4; ++nt)
                        crow[nt * 16] = f2bf(fmaxf(acc[mt][nt][r] + bv[nt], 0.f));
                }
            }
        }
    }
}

// layer-1 aggregation over Xs (bf16, 128 feat, 4B/lane): Xa[v] = bf16(dis[v]*(Σ_N Xs[u] + Xs[v]))
__global__ __launch_bounds__(256) void agg128_kernel(
        const unsigned short* __restrict__ Xs, const int* __restrict__ row_ptr,
        const int* __restrict__ col, const float* __restrict__ dis,
        unsigned short* __restrict__ Xa, int n) {
    int node = blockIdx.x * 4 + (threadIdx.x >> 6);
    if (node >= n) return;
    int lane = threadIdx.x & 63;
    const unsigned int* Xv = (const unsigned int*)Xs;
    unsigned int p = Xv[(size_t)node * 64 + lane];  // self loop
    float ax = bflo(p), ay = bfhi(p);
    int e = row_ptr[node], end = row_ptr[node + 1];
    for (; e + 7 < end; e += 8) {
        unsigned int m[8];
        #pragma unroll
        for (int j = 0; j < 8; ++j) m[j] = Xv[(size_t)col[e + j] * 64 + lane];
        #pragma unroll
        for (int j = 0; j < 8; ++j) { ax += bflo(m[j]); ay += bfhi(m[j]); }
    }
    for (; e < end; ++e) {
        unsigned int m = Xv[(size_t)col[e] * 64 + lane];
        ax += bflo(m); ay += bfhi(m);
    }
    float dv = dis[node];
    unsigned int o = (unsigned int)f2bf(dv * ax) | ((unsigned int)f2bf(dv * ay) << 16);
    ((unsigned int*)Xa)[(size_t)node * 64 + lane] = o;
}

// layers 2,3 aggregation over Hs (bf16, 256 feat, 8B/lane): G[v] = bf16(dis[v]*(Σ_N Hs[u] + Hs[v]))
__global__ __launch_bounds__(256) void agg256_kernel(
        const unsigned short* __restrict__ Hs, const int* __restrict__ row_ptr,
        const int* __restrict__ col, const float* __restrict__ dis,
        unsigned short* __restrict__ G, int n) {
    int node = blockIdx.x * 4 + (threadIdx.x >> 6);
    if (node >= n) return;
    int lane = threadIdx.x & 63;
    const uint2* Hv = (const uint2*)Hs;
    uint2 p = Hv[(size_t)node * 64 + lane];
    float4 acc = make_float4(bflo(p.x), bfhi(p.x), bflo(p.y), bfhi(p.y));
    int e = row_ptr[node], end = row_ptr[node + 1];
    for (; e + 7 < end; e += 8) {
        uint2 m[8];
        #pragma unroll
        for (int j = 0; j < 8; ++j) m[j] = Hv[(size_t)col[e + j] * 64 + lane];
        #pragma unroll
        for (int j = 0; j < 8; ++j) {
            acc.x += bflo(m[j].x); acc.y += bfhi(m[j].x);
            acc.z += bflo(m[j].y); acc.w += bfhi(m[j].y);
        }
    }
    for (; e < end; ++e) {
        uint2 m = Hv[(size_t)col[e] * 64 + lane];
        acc.x += bflo(m.x); acc.y += bfhi(m.x);
        acc.z += bflo(m.y); acc.w += bfhi(m.y);
    }
    float dv = dis[node];
    ushort4 o;
    o.x = f2bf(dv * acc.x); o.y = f2bf(dv * acc.y);
    o.z = f2bf(dv * acc.z); o.w = f2bf(dv * acc.w);
    ((ushort4*)G)[(size_t)node * 64 + lane] = o;
}

// one block per graph: mean-pool (bf16 Hf) + concat + FC1(relu) + FC2
__global__ __launch_bounds__(256) void pool_mlp_kernel(
        const unsigned short* __restrict__ H, const int* __restrict__ goff,
        const float* __restrict__ mol, const float* __restrict__ rings,
        const float* __restrict__ fcW1, const float* __restrict__ fcb1,
        const float* __restrict__ fcW2, const float* __restrict__ fcb2,
        float* __restrict__ out) {
    __shared__ float s_hg[258];
    __shared__ float s_t[196];
    int g = blockIdx.x, tid = threadIdx.x;
    int beg = goff[g], end = goff[g + 1];
    float acc = 0.f;
    for (int i = beg; i < end; ++i) acc += bf2f(H[(size_t)i * HID + tid]);
    s_hg[tid] = acc / fmaxf((float)(end - beg), 1.0f);
    if (tid == 0) { s_hg[256] = mol[g]; s_hg[257] = rings[g]; }
    __syncthreads();
    if (tid < 196) {
        float a = fcb1[tid];
        for (int k = 0; k < 258; ++k) a = fmaf(s_hg[k], fcW1[k * 196 + tid], a);
        s_t[tid] = fmaxf(a, 0.f);
    }
    __syncthreads();
    if (tid < 16) {
        float a = fcb2[tid];
        for (int k = 0; k < 196; ++k) a = fmaf(s_t[k], fcW2[k * 16 + tid], a);
        out[g * 16 + tid] = a;
    }
}

extern "C" void kernel_launch(void* const* d_in, const int* in_sizes, int n_in,
                              void* d_out, int out_size, void* d_ws, size_t ws_size,
                              hipStream_t stream) {
    const float* x     = (const float*)d_in[0];
    const int*   ei    = (const int*)d_in[1];
    const int*   batch = (const int*)d_in[2];
    const float* mol   = (const float*)d_in[3];
    const float* rings = (const float*)d_in[4];
    const float* W1 = (const float*)d_in[5];
    const float* b1 = (const float*)d_in[6];
    const float* W2 = (const float*)d_in[7];
    const float* b2 = (const float*)d_in[8];
    const float* W3 = (const float*)d_in[9];
    const float* b3 = (const float*)d_in[10];
    const float* fcW1 = (const float*)d_in[11];
    const float* fcb1 = (const float*)d_in[12];
    const float* fcW2 = (const float*)d_in[13];
    const float* fcb2 = (const float*)d_in[14];
    float* out = (float*)d_out;
    const int* src = ei;
    const int* dst = ei + NE;

    char* w = (char*)d_ws;
    auto alloc = [&](size_t bytes) {
        char* p = w;
        w += (bytes + 255) & ~(size_t)255;
        return p;
    };
    int*   gbuk    = (int*)alloc((size_t)NBUK * 4);
    int*   bukoff  = (int*)alloc((size_t)(NBUK + 1) * 4);
    int*   bukcur  = (int*)alloc((size_t)NBUK * 4);
    int*   row_ptr = (int*)alloc((size_t)(NN + 1) * 4);
    int*   goff    = (int*)alloc((size_t)(NG + 1) * 4);
    float* dis     = (float*)alloc((size_t)NN * 4);
    unsigned int* pairs = (unsigned int*)alloc((size_t)NE * 4);
    int*   col     = (int*)alloc((size_t)NE * 4);
    unsigned short* Xs  = (unsigned short*)alloc((size_t)NN * FIN * 2);
    unsigned short* Xa  = (unsigned short*)alloc((size_t)NN * FIN * 2);
    unsigned short* Hs  = (unsigned short*)alloc((size_t)NN * HID * 2);
    unsigned short* Ga  = (unsigned short*)alloc((size_t)NN * HID * 2);
    unsigned short* Hf  = (unsigned short*)alloc((size_t)NN * HID * 2);
    unsigned short* W1t = (unsigned short*)alloc((size_t)FIN * HID * 2);
    unsigned short* W2t = (unsigned short*)alloc((size_t)HID * HID * 2);
    unsigned short* W3t = (unsigned short*)alloc((size_t)HID * HID * 2);

    hipMemsetAsync(gbuk, 0, (size_t)NBUK * 4, stream);
    int eb = cdiv(NE, 2048);  // 391
    hist_bucket_kernel<<<eb, 256, 0, stream>>>(dst, gbuk);
    goff_bukscan_kernel<<<197, 256, 0, stream>>>(batch, goff, gbuk, bukoff, bukcur);
    scatter_kernel<<<eb, 256, 0, stream>>>(src, dst, bukcur, pairs);
    local_csr_kernel<<<NBUK, 256, 0, stream>>>(pairs, bukoff, row_ptr, col, dis);

    int ctotal = CAST1 + (FIN + 2 * HID) * 256;
    castall_kernel<<<cdiv(ctotal, 256), 256, 0, stream>>>(x, dis, Xs, W1, W2, W3, W1t, W2t, W3t);

    dim3 ggrid(cdiv(NN, 128), 2);
    int agrid = cdiv(NN, 4);
    // all layers: aggregate-then-transform (aggregation commutes with @W)
    agg128_kernel<<<agrid, 256, 0, stream>>>(Xs, row_ptr, col, dis, Xa, NN);
    gemm128_kernel<0><<<ggrid, 256, 0, stream>>>(Xa, W1t, dis, b1, Hs, NN, FIN);
    agg256_kernel<<<agrid, 256, 0, stream>>>(Hs, row_ptr, col, dis, Ga, NN);
    gemm128_kernel<0><<<ggrid, 256, 0, stream>>>(Ga, W2t, dis, b2, Hs, NN, HID);
    agg256_kernel<<<agrid, 256, 0, stream>>>(Hs, row_ptr, col, dis, Ga, NN);
    gemm128_kernel<1><<<ggrid, 256, 0, stream>>>(Ga, W3t, dis, b3, Hf, NN, HID);
    pool_mlp_kernel<<<NG, 256, 0, stream>>>(Hf, goff, mol, rings, fcW1, fcb1, fcW2, fcb2, out);
}